// Round 5
// baseline (592.295 us; speedup 1.0000x reference)
//
#include <hip/hip_runtime.h>
#include <math.h>

#define KK 25      // KS*KS
#define H1C 32
#define H2C 64
#define FCC 128
#define NCLS 10
#define NG 64
#define M1 32      // nodes per block, layer-1 kernel
#define M2 8       // nodes per block, layer-2 kernel
#define SROW 800   // S row stride (no pad: broadcast reads + 2-way writes are free)
#define ECH1 512   // staged edges per chunk, l1 (8 KB)
#define ECH2 256   // staged edges per chunk, l2 (4 KB)

// ---------------- degree + graph-count histograms ----------------
__global__ void deg_cnt_kernel(const int* __restrict__ edge_index, int E,
                               const int* __restrict__ batch, int N,
                               int* __restrict__ degi, float* __restrict__ cnt) {
    int i = blockIdx.x * blockDim.x + threadIdx.x;
    if (i < E) atomicAdd(&degi[edge_index[E + i]], 1);
    if (i < N) atomicAdd(&cnt[batch[i]], 1.0f);
}

// ---------------- prefix-sum (3-kernel) over degi -> rowst, cur ----------------
__global__ void scan1_kernel(const int* __restrict__ degi, int N,
                             int* __restrict__ incl, int* __restrict__ bsum) {
    __shared__ int s[256];
    int tid = threadIdx.x;
    int i = blockIdx.x * 256 + tid;
    int v = (i < N) ? degi[i] : 0;
    s[tid] = v;
    __syncthreads();
    for (int off = 1; off < 256; off <<= 1) {
        int t = (tid >= off) ? s[tid - off] : 0;
        __syncthreads();
        s[tid] += t;
        __syncthreads();
    }
    if (i < N) incl[i] = s[tid];
    if (tid == 255) bsum[blockIdx.x] = s[255];
}

__global__ void scan2_kernel(int* __restrict__ bsum, int nb) {
    __shared__ int s[256];
    int tid = threadIdx.x;
    int v = (tid < nb) ? bsum[tid] : 0;
    s[tid] = v;
    __syncthreads();
    for (int off = 1; off < 256; off <<= 1) {
        int t = (tid >= off) ? s[tid - off] : 0;
        __syncthreads();
        s[tid] += t;
        __syncthreads();
    }
    if (tid < nb) bsum[tid] = s[tid] - v;   // exclusive
}

__global__ void scan3_kernel(const int* __restrict__ incl, const int* __restrict__ degi,
                             const int* __restrict__ bsum, int N,
                             int* __restrict__ rowst, int* __restrict__ cur) {
    int i = blockIdx.x * 256 + threadIdx.x;
    if (i >= N) return;
    int r = incl[i] - degi[i] + bsum[blockIdx.x];
    rowst[i] = r;
    cur[i] = r;
}

// ---------------- bucket edges by dst; 16B packed {src, dst<<8|kbase, f0, f1} --
__global__ void bucket_kernel(const float* __restrict__ edge_attr,
                              const int* __restrict__ edge_index, int E,
                              int* __restrict__ cur, int4* __restrict__ es) {
    int e = blockIdx.x * blockDim.x + threadIdx.x;
    if (e >= E) return;
    float v0 = edge_attr[2 * e + 0] * 4.0f;
    float v1 = edge_attr[2 * e + 1] * 4.0f;
    int k0 = (int)floorf(v0); k0 = min(max(k0, 0), 3);
    int k1 = (int)floorf(v1); k1 = min(max(k1, 0), 3);
    float f0 = v0 - (float)k0, f1 = v1 - (float)k1;
    int dst = edge_index[E + e];
    int pos = atomicAdd(&cur[dst], 1);
    es[pos] = make_int4(edge_index[e], (dst << 8) | (k0 + 5 * k1),
                        __float_as_int(f0), __float_as_int(f1));
}

// ---------------- layer 1: edge-parallel LDS-atomic accumulation ----------------
// 256 threads; half-wave (32 lanes) = one edge; lane = output channel o.
__global__ __launch_bounds__(256) void l1_kernel(
    const float* __restrict__ x,
    const int* __restrict__ rowst, const int* __restrict__ degi,
    const int4* __restrict__ es,
    const float* __restrict__ W1, const float* __restrict__ root1,
    const float* __restrict__ b1, int N, int E, float* __restrict__ h1) {
    __shared__ float w1s[KK * H1C];
    __shared__ float hbuf[M1 * H1C];
    __shared__ int4 ebuf[ECH1];
    int tid = threadIdx.x;
    for (int i = tid; i < KK * H1C; i += 256) w1s[i] = W1[i];
    for (int i = tid; i < M1 * H1C; i += 256) hbuf[i] = 0.0f;
    int n0 = blockIdx.x * M1;
    int h = tid >> 5, o = tid & 31;
    int blkBeg = rowst[n0];
    int blkEnd = (n0 + M1 < N) ? rowst[n0 + M1] : E;
    for (int base = blkBeg; base < blkEnd; base += ECH1) {
        int m = min(ECH1, blkEnd - base);
        __syncthreads();
        for (int i = tid; i < m; i += 256) ebuf[i] = es[base + i];
        __syncthreads();
        for (int i = h; i < m; i += 16) {           // edges i and i+8 (unroll 2)
            int4 edA = ebuf[i];
            int iB = i + 8;
            bool hasB = iB < m;
            int4 edB = hasB ? ebuf[iB] : edA;
            float xA = x[edA.x];
            float xB = x[edB.x];
            {
                float f0 = __int_as_float(edA.z), f1 = __int_as_float(edA.w);
                float g0 = 1.0f - f0, g1 = 1.0f - f1;
                int kb = (edA.y & 0xff) * H1C + o;
                float coef = g0 * g1 * w1s[kb] + f0 * g1 * w1s[kb + H1C] +
                             g0 * f1 * w1s[kb + 5 * H1C] + f0 * f1 * w1s[kb + 6 * H1C];
                atomicAdd(&hbuf[((edA.y >> 8) - n0) * H1C + o], xA * coef);
            }
            if (hasB) {
                float f0 = __int_as_float(edB.z), f1 = __int_as_float(edB.w);
                float g0 = 1.0f - f0, g1 = 1.0f - f1;
                int kb = (edB.y & 0xff) * H1C + o;
                float coef = g0 * g1 * w1s[kb] + f0 * g1 * w1s[kb + H1C] +
                             g0 * f1 * w1s[kb + 5 * H1C] + f0 * f1 * w1s[kb + 6 * H1C];
                atomicAdd(&hbuf[((edB.y >> 8) - n0) * H1C + o], xB * coef);
            }
        }
    }
    __syncthreads();
    // finalize: 256 threads cover M1*32 = 1024 outputs (4 nodes apart)
    for (int j = 0; j < M1 / 8; j++) {
        int ln = h + 8 * j;
        int n = n0 + ln;
        if (n >= N) break;
        float rdeg = 1.0f / fmaxf((float)degi[n], 1.0f);
        h1[n * H1C + o] = fmaxf(hbuf[ln * H1C + o] * rdeg + x[n] * root1[o] + b1[o], 0.0f);
    }
}

// ---------------- layer 2 fused: edge-parallel S-build + redundancy-free GEMM
// 256 threads. Build: half-wave = edge, lane = channel c. GEMM: thread=(o,ks).
__global__ __launch_bounds__(256) void l2_kernel(
    const float* __restrict__ h1,
    const int* __restrict__ rowst, const int* __restrict__ degi,
    const int4* __restrict__ es,
    const float* __restrict__ W2,     // [(k*32+c)*64+o]
    const float* __restrict__ root2,  // [c*64+o]
    const float* __restrict__ b2,
    const int* __restrict__ batch,
    int N, int E, float* __restrict__ gsum) {
    __shared__ float S[M2 * SROW];    // 25.6 KB
    __shared__ int4 ebuf[ECH2];       // 4 KB (later reused as h2buf)
    int tid = threadIdx.x;
    int n0 = blockIdx.x * M2;
    for (int i = tid; i < M2 * SROW; i += 256) S[i] = 0.0f;

    // ---- build: edge-parallel, ds_add_f32, unroll 2 for MLP
    {
        int h = tid >> 5, c = tid & 31;
        int blkBeg = rowst[n0];
        int blkEnd = (n0 + M2 < N) ? rowst[n0 + M2] : E;
        for (int base = blkBeg; base < blkEnd; base += ECH2) {
            int m = min(ECH2, blkEnd - base);
            __syncthreads();          // guards S zero-init / previous ebuf reads
            for (int i = tid; i < m; i += 256) ebuf[i] = es[base + i];
            __syncthreads();
            for (int i = h; i < m; i += 16) {       // edges i and i+8
                int4 edA = ebuf[i];
                int iB = i + 8;
                bool hasB = iB < m;
                int4 edB = hasB ? ebuf[iB] : edA;
                float hA = h1[edA.x * H1C + c];
                float hB = h1[edB.x * H1C + c];
                {
                    float f0 = __int_as_float(edA.z), f1 = __int_as_float(edA.w);
                    float g0 = 1.0f - f0, g1 = 1.0f - f1;
                    float* Sr = &S[((edA.y >> 8) - n0) * SROW + (edA.y & 0xff) * H1C + c];
                    atomicAdd(&Sr[0],        g0 * g1 * hA);
                    atomicAdd(&Sr[H1C],      f0 * g1 * hA);
                    atomicAdd(&Sr[5 * H1C],  g0 * f1 * hA);
                    atomicAdd(&Sr[6 * H1C],  f0 * f1 * hA);
                }
                if (hasB) {
                    float f0 = __int_as_float(edB.z), f1 = __int_as_float(edB.w);
                    float g0 = 1.0f - f0, g1 = 1.0f - f1;
                    float* Sr = &S[((edB.y >> 8) - n0) * SROW + (edB.y & 0xff) * H1C + c];
                    atomicAdd(&Sr[0],        g0 * g1 * hB);
                    atomicAdd(&Sr[H1C],      f0 * g1 * hB);
                    atomicAdd(&Sr[5 * H1C],  g0 * f1 * hB);
                    atomicAdd(&Sr[6 * H1C],  f0 * f1 * hB);
                }
            }
        }
    }
    __syncthreads();

    // ---- GEMM: thread = (o 0..63, ks 0..3); acc over 8 nodes in registers.
    // W2 loaded exactly once per block (coalesced); S reads wave-uniform broadcast.
    int o = tid & 63;
    int ks = tid >> 6;                 // == wave id
    float acc[M2];
#pragma unroll
    for (int g = 0; g < M2; g++) acc[g] = 0.0f;
    const float* Wp = W2 + o;
    for (int kc = ks * 200; kc < ks * 200 + 200; kc += 4) {
        float w0 = Wp[(kc + 0) * H2C];
        float w1 = Wp[(kc + 1) * H2C];
        float w2 = Wp[(kc + 2) * H2C];
        float w3 = Wp[(kc + 3) * H2C];
#pragma unroll
        for (int g = 0; g < M2; g++) {
            float4 sv = *(const float4*)&S[g * SROW + kc];   // broadcast
            acc[g] = fmaf(sv.x, w0, acc[g]);
            acc[g] = fmaf(sv.y, w1, acc[g]);
            acc[g] = fmaf(sv.z, w2, acc[g]);
            acc[g] = fmaf(sv.w, w3, acc[g]);
        }
    }
    __syncthreads();                   // all S reads done -> reuse S as red[4][8][64]
    float* red = S;
#pragma unroll
    for (int g = 0; g < M2; g++) red[(ks * M2 + g) * H2C + o] = acc[g];
    __syncthreads();

    // ---- reduce + epilogue: thread handles 2 (g,o) pairs
    float* h2buf = (float*)ebuf;       // [M2][64] = 2 KB
    {
        int g = tid >> 5;              // 0..7
        int o0 = (tid & 31) * 2;       // even channel
        int n = n0 + g;
        float2 hv = make_float2(0.0f, 0.0f);
        if (n < N) {
            float s0 = red[g * H2C + o0]       + red[(M2 + g) * H2C + o0] +
                       red[(2 * M2 + g) * H2C + o0] + red[(3 * M2 + g) * H2C + o0];
            float s1 = red[g * H2C + o0 + 1]   + red[(M2 + g) * H2C + o0 + 1] +
                       red[(2 * M2 + g) * H2C + o0 + 1] + red[(3 * M2 + g) * H2C + o0 + 1];
            float rd = 1.0f / fmaxf((float)degi[n], 1.0f);
            hv.x = s0 * rd + b2[o0];
            hv.y = s1 * rd + b2[o0 + 1];
            const float* hrow = h1 + n * H1C;
#pragma unroll 8
            for (int c = 0; c < H1C; c++) {
                float2 rt = *(const float2*)&root2[c * H2C + o0];
                float hc = hrow[c];
                hv.x = fmaf(hc, rt.x, hv.x);
                hv.y = fmaf(hc, rt.y, hv.y);
            }
            hv.x = fmaxf(hv.x, 0.0f);
            hv.y = fmaxf(hv.y, 0.0f);
        }
        __syncthreads();               // red reads done before h2buf write (alias-safe: different buffers, but keep order tight)
        *(float2*)&h2buf[g * H2C + o0] = hv;
    }
    __syncthreads();

    // ---- pool: block-local per-graph reduction, one atomic per (graph,o)
    if (tid < H2C) {
        int o2 = tid;
        float run = 0.0f;
        int curg = batch[min(n0, N - 1)];
        for (int ln = 0; ln < M2; ln++) {
            int n = n0 + ln;
            if (n >= N) break;
            int g = batch[n];
            if (g != curg) {
                atomicAdd(&gsum[curg * H2C + o2], run);
                run = 0.0f;
                curg = g;
            }
            run += h2buf[ln * H2C + o2];
        }
        atomicAdd(&gsum[curg * H2C + o2], run);
    }
}

// ---------------- head: mean, FC1+relu, FC2, log_softmax ----------------
__global__ void head_kernel(const float* __restrict__ gsum, const float* __restrict__ cnt,
                            const float* __restrict__ Wf1, const float* __restrict__ bf1,
                            const float* __restrict__ Wf2, const float* __restrict__ bf2,
                            float* __restrict__ out) {
    __shared__ float gc[H2C];
    __shared__ float t1[FCC];
    __shared__ float lg[NCLS];
    __shared__ float lse;
    int g = blockIdx.x, tid = threadIdx.x;
    if (tid < H2C) gc[tid] = gsum[g * H2C + tid] / fmaxf(cnt[g], 1.0f);
    __syncthreads();
    {
        float acc = bf1[tid];
        for (int c = 0; c < H2C; c++) acc += gc[c] * Wf1[c * FCC + tid];
        t1[tid] = fmaxf(acc, 0.0f);
    }
    __syncthreads();
    if (tid < NCLS) {
        float acc = bf2[tid];
        for (int j = 0; j < FCC; j++) acc += t1[j] * Wf2[j * NCLS + tid];
        lg[tid] = acc;
    }
    __syncthreads();
    if (tid == 0) {
        float m = lg[0];
        for (int c = 1; c < NCLS; c++) m = fmaxf(m, lg[c]);
        float s = 0.0f;
        for (int c = 0; c < NCLS; c++) s += expf(lg[c] - m);
        lse = m + logf(s);
    }
    __syncthreads();
    if (tid < NCLS) out[g * NCLS + tid] = lg[tid] - lse;
}

extern "C" void kernel_launch(void* const* d_in, const int* in_sizes, int n_in,
                              void* d_out, int out_size, void* d_ws, size_t ws_size,
                              hipStream_t stream) {
    const float* x          = (const float*)d_in[0];
    const float* edge_attr  = (const float*)d_in[1];
    const float* W1         = (const float*)d_in[2];
    const float* root1      = (const float*)d_in[3];
    const float* b1         = (const float*)d_in[4];
    const float* W2         = (const float*)d_in[5];
    const float* root2      = (const float*)d_in[6];
    const float* b2         = (const float*)d_in[7];
    const float* Wf1        = (const float*)d_in[8];
    const float* bf1        = (const float*)d_in[9];
    const float* Wf2        = (const float*)d_in[10];
    const float* bf2        = (const float*)d_in[11];
    const int*   edge_index = (const int*)d_in[12];
    const int*   batch      = (const int*)d_in[13];
    float* out = (float*)d_out;

    const int N = in_sizes[13];       // 20000
    const int E = in_sizes[12] / 2;   // 320000
    const int NB = (N + 255) / 256;   // scan blocks (79)

    // -------- workspace layout --------
    int4*  es    = (int4*)d_ws;                      // E packed sorted edges
    float* gsum  = (float*)(es + E);                 // NG*H2C  -- zero block start
    float* cnt   = gsum + NG * H2C;                  // NG
    int*   degi  = (int*)(cnt + NG);                 // N       -- zero block end
    int*   rowst = degi + N;                         // N
    int*   cur   = rowst + N;                        // N
    int*   incl  = cur + N;                          // N
    int*   bsum  = incl + N;                         // 256
    float* h1    = (float*)(bsum + 256);             // N*H1C

    size_t zero_elems = (size_t)NG * H2C + NG + N;
    hipMemsetAsync(gsum, 0, zero_elems * sizeof(float), stream);

    deg_cnt_kernel<<<(E + 255) / 256, 256, 0, stream>>>(edge_index, E, batch, N, degi, cnt);

    scan1_kernel<<<NB, 256, 0, stream>>>(degi, N, incl, bsum);
    scan2_kernel<<<1, 256, 0, stream>>>(bsum, NB);
    scan3_kernel<<<NB, 256, 0, stream>>>(incl, degi, bsum, N, rowst, cur);

    bucket_kernel<<<(E + 255) / 256, 256, 0, stream>>>(edge_attr, edge_index, E, cur, es);

    l1_kernel<<<(N + M1 - 1) / M1, 256, 0, stream>>>(
        x, rowst, degi, es, W1, root1, b1, N, E, h1);

    l2_kernel<<<(N + M2 - 1) / M2, 256, 0, stream>>>(
        h1, rowst, degi, es, W2, root2, b2, batch, N, E, gsum);

    head_kernel<<<NG, FCC, 0, stream>>>(gsum, cnt, Wf1, bf1, Wf2, bf2, out);
}

// Round 6
// 444.866 us; speedup vs baseline: 1.3314x; 1.3314x over previous
//
#include <hip/hip_runtime.h>
#include <hip/hip_fp16.h>
#include <math.h>

#define KK 25
#define H1C 32
#define H2C 64
#define FCC 128
#define NCLS 10
#define NG 64
#define M1 32      // nodes per block, layer-1
#define M2 16      // nodes per block, layer-2

typedef __fp16 half2v __attribute__((ext_vector_type(2)));
static __device__ inline unsigned pkh(float a, float b) {
    half2v h = __builtin_amdgcn_cvt_pkrtz(a, b);
    return __builtin_bit_cast(unsigned, h);
}

// ---------------- degree + graph-count histograms ----------------
__global__ void deg_cnt_kernel(const int* __restrict__ edge_index, int E,
                               const int* __restrict__ batch, int N,
                               int* __restrict__ degi, float* __restrict__ cnt) {
    int i = blockIdx.x * blockDim.x + threadIdx.x;
    if (i < E) atomicAdd(&degi[edge_index[E + i]], 1);
    if (i < N) atomicAdd(&cnt[batch[i]], 1.0f);
}

// ---------------- prefix-sum (3-kernel) over degi -> rowst, cur ----------------
__global__ void scan1_kernel(const int* __restrict__ degi, int N,
                             int* __restrict__ incl, int* __restrict__ bsum) {
    __shared__ int s[256];
    int tid = threadIdx.x;
    int i = blockIdx.x * 256 + tid;
    int v = (i < N) ? degi[i] : 0;
    s[tid] = v;
    __syncthreads();
    for (int off = 1; off < 256; off <<= 1) {
        int t = (tid >= off) ? s[tid - off] : 0;
        __syncthreads();
        s[tid] += t;
        __syncthreads();
    }
    if (i < N) incl[i] = s[tid];
    if (tid == 255) bsum[blockIdx.x] = s[255];
}

__global__ void scan2_kernel(int* __restrict__ bsum, int nb) {
    __shared__ int s[256];
    int tid = threadIdx.x;
    int v = (tid < nb) ? bsum[tid] : 0;
    s[tid] = v;
    __syncthreads();
    for (int off = 1; off < 256; off <<= 1) {
        int t = (tid >= off) ? s[tid - off] : 0;
        __syncthreads();
        s[tid] += t;
        __syncthreads();
    }
    if (tid < nb) bsum[tid] = s[tid] - v;   // exclusive
}

__global__ void scan3_kernel(const int* __restrict__ incl, const int* __restrict__ degi,
                             const int* __restrict__ bsum, int N,
                             int* __restrict__ rowst, int* __restrict__ cur) {
    int i = blockIdx.x * 256 + threadIdx.x;
    if (i >= N) return;
    int r = incl[i] - degi[i] + bsum[blockIdx.x];
    rowst[i] = r;
    cur[i] = r;
}

// ---------------- bucket edges by dst; 16B packed {src, dst<<8|kbase, f0, f1} --
__global__ void bucket_kernel(const float* __restrict__ edge_attr,
                              const int* __restrict__ edge_index, int E,
                              int* __restrict__ cur, int4* __restrict__ es) {
    int e = blockIdx.x * blockDim.x + threadIdx.x;
    if (e >= E) return;
    float v0 = edge_attr[2 * e + 0] * 4.0f;
    float v1 = edge_attr[2 * e + 1] * 4.0f;
    int k0 = (int)floorf(v0); k0 = min(max(k0, 0), 3);
    int k1 = (int)floorf(v1); k1 = min(max(k1, 0), 3);
    float f0 = v0 - (float)k0, f1 = v1 - (float)k1;
    int dst = edge_index[E + e];
    int pos = atomicAdd(&cur[dst], 1);
    es[pos] = make_int4(edge_index[e], (dst << 8) | (k0 + 5 * k1),
                        __float_as_int(f0), __float_as_int(f1));
}

// ---------------- layer 1: CSR gather, register accumulate, boundary flush ----
// 256 thr = 8 groups x 32 lanes(o). Group walks a contiguous edge sub-range.
__global__ __launch_bounds__(256) void l1_kernel(
    const float* __restrict__ x,
    const int* __restrict__ rowst, const int* __restrict__ degi,
    const int4* __restrict__ es,
    const float* __restrict__ W1, const float* __restrict__ root1,
    const float* __restrict__ b1, int N, int E, float* __restrict__ h1) {
    __shared__ float w1s[KK * H1C];     // 3.2 KB
    __shared__ float agg1[M1 * H1C];    // 4 KB
    __shared__ int4 eb[8][32];          // 4 KB
    __shared__ float xb[8][32];         // 1 KB
    int tid = threadIdx.x;
    for (int i = tid; i < KK * H1C; i += 256) w1s[i] = W1[i];
    for (int i = tid; i < M1 * H1C; i += 256) agg1[i] = 0.0f;
    __syncthreads();
    int g = tid >> 5, o = tid & 31;
    int n0 = blockIdx.x * M1;
    int blkBeg = rowst[n0];
    int blkEnd = (n0 + M1 < N) ? rowst[n0 + M1] : E;
    int total = blkEnd - blkBeg;
    int per = (total + 7) >> 3;
    int wBeg = blkBeg + g * per;
    int wEnd = min(blkEnd, wBeg + per);
    int curDst = -1;
    float acc = 0.0f;
    for (int base = wBeg; base < wEnd; base += 32) {
        int m = min(32, wEnd - base);
        if (o < m) {
            int4 ed = es[base + o];
            eb[g][o] = ed;
            xb[g][o] = x[ed.x];
        }
        for (int j = 0; j < m; j++) {
            int4 ed = eb[g][j];          // 32-lane broadcast ds_read
            float xs = xb[g][j];
            int dst = ed.y >> 8;
            if (dst != curDst) {
                if (curDst >= 0) atomicAdd(&agg1[(curDst - n0) * H1C + o], acc);
                acc = 0.0f;
                curDst = dst;
            }
            float f0 = __int_as_float(ed.z), f1 = __int_as_float(ed.w);
            float g0 = 1.0f - f0, g1 = 1.0f - f1;
            int kb = (ed.y & 0xff) << 5;  // *32
            float coef = g0 * g1 * w1s[kb + o] + f0 * g1 * w1s[kb + 32 + o] +
                         g0 * f1 * w1s[kb + 160 + o] + f0 * f1 * w1s[kb + 192 + o];
            acc = fmaf(xs, coef, acc);
        }
    }
    if (curDst >= 0) atomicAdd(&agg1[(curDst - n0) * H1C + o], acc);
    __syncthreads();
#pragma unroll
    for (int i = 0; i < 4; i++) {
        int ln = g + 8 * i;
        int n = n0 + ln;
        if (n < N) {
            float rdeg = 1.0f / fmaxf((float)degi[n], 1.0f);
            h1[n * H1C + o] = fmaxf(agg1[ln * H1C + o] * rdeg + x[n] * root1[o] + b1[o], 0.0f);
        }
    }
}

// ---------------- xW2 (fp16) = h1 @ W2 : [N][25][64] halfs ----------------
// 256 thr = 32 nodes x 8 oq(8ch). h-row in VGPRs; W2 via L1-hot broadcast loads.
__global__ __launch_bounds__(256) void xw2f_kernel(
    const float* __restrict__ h1, const float* __restrict__ W2,
    int N, unsigned* __restrict__ xph) {   // uint = 2 halfs
    int tid = threadIdx.x;
    int n = blockIdx.x * 32 + (tid >> 3);
    int oq = tid & 7;
    if (n >= N) return;
    float hrow[H1C];
    const float4* hp = (const float4*)(h1 + n * H1C);
#pragma unroll
    for (int i = 0; i < 8; i++) {
        float4 v = hp[i];
        hrow[4 * i] = v.x; hrow[4 * i + 1] = v.y;
        hrow[4 * i + 2] = v.z; hrow[4 * i + 3] = v.w;
    }
    unsigned* outp = xph + (size_t)n * 800 + oq * 4;
    for (int k = 0; k < KK; k++) {
        const float* wp = W2 + k * (H1C * H2C) + oq * 8;
        float a0 = 0, a1 = 0, a2 = 0, a3 = 0, a4 = 0, a5 = 0, a6 = 0, a7 = 0;
#pragma unroll 8
        for (int c = 0; c < H1C; c++) {
            float4 wA = *(const float4*)(wp + c * H2C);
            float4 wB = *(const float4*)(wp + c * H2C + 4);
            float h = hrow[c];
            a0 = fmaf(h, wA.x, a0); a1 = fmaf(h, wA.y, a1);
            a2 = fmaf(h, wA.z, a2); a3 = fmaf(h, wA.w, a3);
            a4 = fmaf(h, wB.x, a4); a5 = fmaf(h, wB.y, a5);
            a6 = fmaf(h, wB.z, a6); a7 = fmaf(h, wB.w, a7);
        }
        uint4 u = make_uint4(pkh(a0, a1), pkh(a2, a3), pkh(a4, a5), pkh(a6, a7));
        *(uint4*)(outp + k * 32) = u;
    }
}

// ---------------- layer 2: gather from xW2h + reg accumulate + epilogue + pool
// 256 thr = 4 waves x 64 lanes(o). Wave walks contiguous edge sub-range.
__global__ __launch_bounds__(256) void l2_kernel(
    const float* __restrict__ h1,
    const int* __restrict__ rowst, const int* __restrict__ degi,
    const int4* __restrict__ es,
    const __half* __restrict__ xph,   // [N][25][64]
    const float* __restrict__ root2, const float* __restrict__ b2,
    const int* __restrict__ batch,
    int N, int E, float* __restrict__ gsum) {
    __shared__ float agg[M2 * H2C];   // 4 KB (reused as h2buf)
    __shared__ int4 eb[4][64];        // 4 KB
    int tid = threadIdx.x;
    for (int i = tid; i < M2 * H2C; i += 256) agg[i] = 0.0f;
    __syncthreads();
    int w = tid >> 6, o = tid & 63;
    int n0 = blockIdx.x * M2;
    int blkBeg = rowst[n0];
    int blkEnd = (n0 + M2 < N) ? rowst[n0 + M2] : E;
    int total = blkEnd - blkBeg;
    int per = (total + 3) >> 2;
    int wBeg = blkBeg + w * per;
    int wEnd = min(blkEnd, wBeg + per);
    int curDst = -1;
    float acc = 0.0f;
    for (int base = wBeg; base < wEnd; base += 64) {
        int m = min(64, wEnd - base);
        if (o < m) eb[w][o] = es[base + o];
        int j = 0;
        for (; j + 1 < m; j += 2) {
            int4 eA = eb[w][j];
            int4 eB = eb[w][j + 1];
            const __half* pA = xph + (size_t)eA.x * (KK * H2C) + ((eA.y & 0xff) << 6) + o;
            const __half* pB = xph + (size_t)eB.x * (KK * H2C) + ((eB.y & 0xff) << 6) + o;
            float tA0 = __half2float(pA[0]);
            float tA1 = __half2float(pA[64]);
            float tA2 = __half2float(pA[320]);
            float tA3 = __half2float(pA[384]);
            float tB0 = __half2float(pB[0]);
            float tB1 = __half2float(pB[64]);
            float tB2 = __half2float(pB[320]);
            float tB3 = __half2float(pB[384]);
            int dstA = eA.y >> 8;
            if (dstA != curDst) {
                if (curDst >= 0) atomicAdd(&agg[(curDst - n0) * H2C + o], acc);
                acc = 0.0f;
                curDst = dstA;
            }
            {
                float f0 = __int_as_float(eA.z), f1 = __int_as_float(eA.w);
                float g0 = 1.0f - f0, g1 = 1.0f - f1;
                acc = fmaf(g0 * g1, tA0, acc);
                acc = fmaf(f0 * g1, tA1, acc);
                acc = fmaf(g0 * f1, tA2, acc);
                acc = fmaf(f0 * f1, tA3, acc);
            }
            int dstB = eB.y >> 8;
            if (dstB != curDst) {
                atomicAdd(&agg[(curDst - n0) * H2C + o], acc);
                acc = 0.0f;
                curDst = dstB;
            }
            {
                float f0 = __int_as_float(eB.z), f1 = __int_as_float(eB.w);
                float g0 = 1.0f - f0, g1 = 1.0f - f1;
                acc = fmaf(g0 * g1, tB0, acc);
                acc = fmaf(f0 * g1, tB1, acc);
                acc = fmaf(g0 * f1, tB2, acc);
                acc = fmaf(f0 * f1, tB3, acc);
            }
        }
        if (j < m) {
            int4 eA = eb[w][j];
            const __half* pA = xph + (size_t)eA.x * (KK * H2C) + ((eA.y & 0xff) << 6) + o;
            float tA0 = __half2float(pA[0]);
            float tA1 = __half2float(pA[64]);
            float tA2 = __half2float(pA[320]);
            float tA3 = __half2float(pA[384]);
            int dstA = eA.y >> 8;
            if (dstA != curDst) {
                if (curDst >= 0) atomicAdd(&agg[(curDst - n0) * H2C + o], acc);
                acc = 0.0f;
                curDst = dstA;
            }
            float f0 = __int_as_float(eA.z), f1 = __int_as_float(eA.w);
            float g0 = 1.0f - f0, g1 = 1.0f - f1;
            acc = fmaf(g0 * g1, tA0, acc);
            acc = fmaf(f0 * g1, tA1, acc);
            acc = fmaf(g0 * f1, tA2, acc);
            acc = fmaf(f0 * f1, tA3, acc);
        }
    }
    if (curDst >= 0) atomicAdd(&agg[(curDst - n0) * H2C + o], acc);
    __syncthreads();

    // epilogue: h2 = relu(agg/deg + h1@root2 + b2), in place in agg
#pragma unroll
    for (int i = 0; i < 4; i++) {
        int ln = w + 4 * i;
        int n = n0 + ln;
        if (n < N) {
            float rd = 1.0f / fmaxf((float)degi[n], 1.0f);
            float v = agg[ln * H2C + o] * rd + b2[o];
            const float* hr = h1 + n * H1C;
#pragma unroll 8
            for (int c = 0; c < H1C; c++) v = fmaf(hr[c], root2[c * H2C + o], v);
            agg[ln * H2C + o] = fmaxf(v, 0.0f);
        } else {
            agg[ln * H2C + o] = 0.0f;
        }
    }
    __syncthreads();

    // pool: one atomic per (graph,o) per block
    if (tid < H2C) {
        float run = 0.0f;
        int curg = batch[n0];
        for (int ln = 0; ln < M2; ln++) {
            int n = n0 + ln;
            if (n >= N) break;
            int gg = batch[n];
            if (gg != curg) {
                atomicAdd(&gsum[curg * H2C + tid], run);
                run = 0.0f;
                curg = gg;
            }
            run += agg[ln * H2C + tid];
        }
        atomicAdd(&gsum[curg * H2C + tid], run);
    }
}

// ---------------- head: mean, FC1+relu, FC2, log_softmax ----------------
__global__ void head_kernel(const float* __restrict__ gsum, const float* __restrict__ cnt,
                            const float* __restrict__ Wf1, const float* __restrict__ bf1,
                            const float* __restrict__ Wf2, const float* __restrict__ bf2,
                            float* __restrict__ out) {
    __shared__ float gc[H2C];
    __shared__ float t1[FCC];
    __shared__ float lg[NCLS];
    __shared__ float lse;
    int g = blockIdx.x, tid = threadIdx.x;
    if (tid < H2C) gc[tid] = gsum[g * H2C + tid] / fmaxf(cnt[g], 1.0f);
    __syncthreads();
    {
        float acc = bf1[tid];
        for (int c = 0; c < H2C; c++) acc += gc[c] * Wf1[c * FCC + tid];
        t1[tid] = fmaxf(acc, 0.0f);
    }
    __syncthreads();
    if (tid < NCLS) {
        float acc = bf2[tid];
        for (int j = 0; j < FCC; j++) acc += t1[j] * Wf2[j * NCLS + tid];
        lg[tid] = acc;
    }
    __syncthreads();
    if (tid == 0) {
        float m = lg[0];
        for (int c = 1; c < NCLS; c++) m = fmaxf(m, lg[c]);
        float s = 0.0f;
        for (int c = 0; c < NCLS; c++) s += expf(lg[c] - m);
        lse = m + logf(s);
    }
    __syncthreads();
    if (tid < NCLS) out[g * NCLS + tid] = lg[tid] - lse;
}

extern "C" void kernel_launch(void* const* d_in, const int* in_sizes, int n_in,
                              void* d_out, int out_size, void* d_ws, size_t ws_size,
                              hipStream_t stream) {
    const float* x          = (const float*)d_in[0];
    const float* edge_attr  = (const float*)d_in[1];
    const float* W1         = (const float*)d_in[2];
    const float* root1      = (const float*)d_in[3];
    const float* b1         = (const float*)d_in[4];
    const float* W2         = (const float*)d_in[5];
    const float* root2      = (const float*)d_in[6];
    const float* b2         = (const float*)d_in[7];
    const float* Wf1        = (const float*)d_in[8];
    const float* bf1        = (const float*)d_in[9];
    const float* Wf2        = (const float*)d_in[10];
    const float* bf2        = (const float*)d_in[11];
    const int*   edge_index = (const int*)d_in[12];
    const int*   batch      = (const int*)d_in[13];
    float* out = (float*)d_out;

    const int N = in_sizes[13];       // 20000
    const int E = in_sizes[12] / 2;   // 320000
    const int NB = (N + 255) / 256;   // scan blocks

    // -------- workspace layout --------
    int4*     es   = (int4*)d_ws;                    // E packed sorted edges (5.1 MB)
    unsigned* xph  = (unsigned*)(es + E);            // N*800 uints = fp16 [N][25][64] (64 MB)
    float* gsum  = (float*)(xph + (size_t)N * 800);  // NG*H2C  -- zero block start
    float* cnt   = gsum + NG * H2C;                  // NG
    int*   degi  = (int*)(cnt + NG);                 // N       -- zero block end
    int*   rowst = degi + N;                         // N
    int*   cur   = rowst + N;                        // N
    int*   incl  = cur + N;                          // N
    int*   bsum  = incl + N;                         // 256
    float* h1    = (float*)(bsum + 256);             // N*H1C

    size_t zero_elems = (size_t)NG * H2C + NG + N;
    hipMemsetAsync(gsum, 0, zero_elems * sizeof(float), stream);

    deg_cnt_kernel<<<(E + 255) / 256, 256, 0, stream>>>(edge_index, E, batch, N, degi, cnt);

    scan1_kernel<<<NB, 256, 0, stream>>>(degi, N, incl, bsum);
    scan2_kernel<<<1, 256, 0, stream>>>(bsum, NB);
    scan3_kernel<<<NB, 256, 0, stream>>>(incl, degi, bsum, N, rowst, cur);

    bucket_kernel<<<(E + 255) / 256, 256, 0, stream>>>(edge_attr, edge_index, E, cur, es);

    l1_kernel<<<(N + M1 - 1) / M1, 256, 0, stream>>>(
        x, rowst, degi, es, W1, root1, b1, N, E, h1);

    xw2f_kernel<<<(N + 31) / 32, 256, 0, stream>>>(h1, W2, N, xph);

    l2_kernel<<<(N + M2 - 1) / M2, 256, 0, stream>>>(
        h1, rowst, degi, es, (const __half*)xph, root2, b2, batch, N, E, gsum);

    head_kernel<<<NG, FCC, 0, stream>>>(gsum, cnt, Wf1, bf1, Wf2, bf2, out);
}

// Round 7
// 327.636 us; speedup vs baseline: 1.8078x; 1.3578x over previous
//
#include <hip/hip_runtime.h>
#include <hip/hip_fp16.h>
#include <math.h>

#define KK 25
#define H1C 32
#define H2C 64
#define FCC 128
#define NCLS 10
#define NG 64
#define M1 32      // nodes per block, layer-1
#define M2 16      // nodes per block, layer-2

typedef _Float16 v8h __attribute__((ext_vector_type(8)));
typedef float v4f __attribute__((ext_vector_type(4)));

// ---------------- degree + graph-count histograms ----------------
__global__ void deg_cnt_kernel(const int* __restrict__ edge_index, int E,
                               const int* __restrict__ batch, int N,
                               int* __restrict__ degi, float* __restrict__ cnt) {
    int i = blockIdx.x * blockDim.x + threadIdx.x;
    if (i < E) atomicAdd(&degi[edge_index[E + i]], 1);
    if (i < N) atomicAdd(&cnt[batch[i]], 1.0f);
}

// ---------------- prefix-sum (3-kernel) over degi -> rowst, cur ----------------
__global__ void scan1_kernel(const int* __restrict__ degi, int N,
                             int* __restrict__ incl, int* __restrict__ bsum) {
    __shared__ int s[256];
    int tid = threadIdx.x;
    int i = blockIdx.x * 256 + tid;
    int v = (i < N) ? degi[i] : 0;
    s[tid] = v;
    __syncthreads();
    for (int off = 1; off < 256; off <<= 1) {
        int t = (tid >= off) ? s[tid - off] : 0;
        __syncthreads();
        s[tid] += t;
        __syncthreads();
    }
    if (i < N) incl[i] = s[tid];
    if (tid == 255) bsum[blockIdx.x] = s[255];
}

__global__ void scan2_kernel(int* __restrict__ bsum, int nb) {
    __shared__ int s[256];
    int tid = threadIdx.x;
    int v = (tid < nb) ? bsum[tid] : 0;
    s[tid] = v;
    __syncthreads();
    for (int off = 1; off < 256; off <<= 1) {
        int t = (tid >= off) ? s[tid - off] : 0;
        __syncthreads();
        s[tid] += t;
        __syncthreads();
    }
    if (tid < nb) bsum[tid] = s[tid] - v;   // exclusive
}

__global__ void scan3_kernel(const int* __restrict__ incl, const int* __restrict__ degi,
                             const int* __restrict__ bsum, int N,
                             int* __restrict__ rowst, int* __restrict__ cur) {
    int i = blockIdx.x * 256 + threadIdx.x;
    if (i >= N) return;
    int r = incl[i] - degi[i] + bsum[blockIdx.x];
    rowst[i] = r;
    cur[i] = r;
}

// ---------------- bucket edges by dst; 16B packed {src, dst<<8|kbase, f0, f1} --
__global__ void bucket_kernel(const float* __restrict__ edge_attr,
                              const int* __restrict__ edge_index, int E,
                              int* __restrict__ cur, int4* __restrict__ es) {
    int e = blockIdx.x * blockDim.x + threadIdx.x;
    if (e >= E) return;
    float v0 = edge_attr[2 * e + 0] * 4.0f;
    float v1 = edge_attr[2 * e + 1] * 4.0f;
    int k0 = (int)floorf(v0); k0 = min(max(k0, 0), 3);
    int k1 = (int)floorf(v1); k1 = min(max(k1, 0), 3);
    float f0 = v0 - (float)k0, f1 = v1 - (float)k1;
    int dst = edge_index[E + e];
    int pos = atomicAdd(&cur[dst], 1);
    es[pos] = make_int4(edge_index[e], (dst << 8) | (k0 + 5 * k1),
                        __float_as_int(f0), __float_as_int(f1));
}

// ---------------- W2 -> fp16 transposed [25][64][32] (c innermost) ----------
__global__ void w2t_kernel(const float* __restrict__ W2, __half* __restrict__ W2t) {
    int idx = blockIdx.x * 256 + threadIdx.x;
    if (idx >= KK * H2C * H1C) return;
    int c = idx & 31, o = (idx >> 5) & 63, k = idx >> 11;
    W2t[idx] = __float2half(W2[(k * H1C + c) * H2C + o]);
}

// ---------------- layer 1: CSR gather, register accumulate, boundary flush ----
// 256 thr = 8 groups x 32 lanes(o). Also emits h1 as fp16 for the MFMA GEMM.
__global__ __launch_bounds__(256) void l1_kernel(
    const float* __restrict__ x,
    const int* __restrict__ rowst, const int* __restrict__ degi,
    const int4* __restrict__ es,
    const float* __restrict__ W1, const float* __restrict__ root1,
    const float* __restrict__ b1, int N, int E,
    float* __restrict__ h1, __half* __restrict__ h1f) {
    __shared__ float w1s[KK * H1C];
    __shared__ float agg1[M1 * H1C];
    __shared__ int4 eb[8][32];
    __shared__ float xb[8][32];
    int tid = threadIdx.x;
    for (int i = tid; i < KK * H1C; i += 256) w1s[i] = W1[i];
    for (int i = tid; i < M1 * H1C; i += 256) agg1[i] = 0.0f;
    __syncthreads();
    int g = tid >> 5, o = tid & 31;
    int n0 = blockIdx.x * M1;
    int blkBeg = rowst[n0];
    int blkEnd = (n0 + M1 < N) ? rowst[n0 + M1] : E;
    int total = blkEnd - blkBeg;
    int per = (total + 7) >> 3;
    int wBeg = blkBeg + g * per;
    int wEnd = min(blkEnd, wBeg + per);
    int curDst = -1;
    float acc = 0.0f;
    for (int base = wBeg; base < wEnd; base += 32) {
        int m = min(32, wEnd - base);
        if (o < m) {
            int4 ed = es[base + o];
            eb[g][o] = ed;
            xb[g][o] = x[ed.x];
        }
        for (int j = 0; j < m; j++) {
            int4 ed = eb[g][j];
            float xs = xb[g][j];
            int dst = ed.y >> 8;
            if (dst != curDst) {
                if (curDst >= 0) atomicAdd(&agg1[(curDst - n0) * H1C + o], acc);
                acc = 0.0f;
                curDst = dst;
            }
            float f0 = __int_as_float(ed.z), f1 = __int_as_float(ed.w);
            float g0 = 1.0f - f0, g1 = 1.0f - f1;
            int kb = (ed.y & 0xff) << 5;
            float coef = g0 * g1 * w1s[kb + o] + f0 * g1 * w1s[kb + 32 + o] +
                         g0 * f1 * w1s[kb + 160 + o] + f0 * f1 * w1s[kb + 192 + o];
            acc = fmaf(xs, coef, acc);
        }
    }
    if (curDst >= 0) atomicAdd(&agg1[(curDst - n0) * H1C + o], acc);
    __syncthreads();
#pragma unroll
    for (int i = 0; i < 4; i++) {
        int ln = g + 8 * i;
        int n = n0 + ln;
        if (n < N) {
            float rdeg = 1.0f / fmaxf((float)degi[n], 1.0f);
            float hv = fmaxf(agg1[ln * H1C + o] * rdeg + x[n] * root1[o] + b1[o], 0.0f);
            h1[n * H1C + o] = hv;
            h1f[n * H1C + o] = __float2half(hv);
        }
    }
}

// ---------------- xW2 via MFMA: [N][25][64] fp16 = h1f @ W2t ----------------
// 256 thr = 4 waves. Block = 16 nodes; wave = one 16-ch o-tile, loops 25 knots.
// A[m=lane&15][k=quad*8+j]; B[k=quad*8+j][n=lane&15]; D col=lane&15 row=quad*4+r.
__global__ __launch_bounds__(256) void xw2m_kernel(
    const __half* __restrict__ h1f,   // [N][32]
    const __half* __restrict__ W2t,   // [25][64][32] (c innermost)
    int N, __half* __restrict__ xph) {  // [N][25][64]
    int wv = threadIdx.x >> 6;
    int lane = threadIdx.x & 63;
    int r15 = lane & 15, quad = lane >> 4;
    int n0 = blockIdx.x * 16;
    int o0 = wv * 16;
    v8h afrag = {};
    int an = n0 + r15;
    if (an < N) afrag = *(const v8h*)(h1f + (size_t)an * H1C + quad * 8);
    for (int k = 0; k < KK; k++) {
        v8h bfrag = *(const v8h*)(W2t + ((k << 6) + o0 + r15) * H1C + quad * 8);
        v4f acc = {};
        acc = __builtin_amdgcn_mfma_f32_16x16x32_f16(afrag, bfrag, acc, 0, 0, 0);
#pragma unroll
        for (int r = 0; r < 4; r++) {
            int mn = n0 + quad * 4 + r;
            if (mn < N)
                xph[(size_t)mn * (KK * H2C) + (k << 6) + o0 + r15] = __float2half(acc[r]);
        }
    }
}

// ---------------- layer 2: half2-packed gather + segment accumulate ----------
// 256 thr = 4 waves; wave = 2 edge-slots (eh) x 32 lanes (o-pair).
__global__ __launch_bounds__(256) void l2_kernel(
    const float* __restrict__ h1,
    const int* __restrict__ rowst, const int* __restrict__ degi,
    const int4* __restrict__ es,
    const unsigned* __restrict__ xphu,  // [N][25][32] uints (=2 halves)
    const float* __restrict__ root2, const float* __restrict__ b2,
    const int* __restrict__ batch,
    int N, int E, float* __restrict__ gsum) {
    __shared__ float agg[M2 * H2C];   // 4 KB (reused as h2buf)
    __shared__ int4 eb[4][64];        // 4 KB
    int tid = threadIdx.x;
    for (int i = tid; i < M2 * H2C; i += 256) agg[i] = 0.0f;
    __syncthreads();
    int w = tid >> 6, lane = tid & 63;
    int o2 = lane & 31, eh = lane >> 5;
    int n0 = blockIdx.x * M2;
    int blkBeg = rowst[n0];
    int blkEnd = (n0 + M2 < N) ? rowst[n0 + M2] : E;
    int total = blkEnd - blkBeg;
    int per = (total + 3) >> 2;
    int wBeg = blkBeg + w * per;
    int wEnd = min(blkEnd, wBeg + per);
    int curDst = -1;
    float ax = 0.0f, ay = 0.0f;
    for (int base = wBeg; base < wEnd; base += 64) {
        int m = min(64, wEnd - base);
        if (lane < m) eb[w][lane] = es[base + lane];
        for (int j = 0; j < m; j += 2) {
            int jj = j + eh;
            bool act = jj < m;
            int4 ed = eb[w][act ? jj : j];
            const unsigned* p = xphu + (size_t)ed.x * (KK * H2C / 2) +
                                ((ed.y & 0xff) << 5) + o2;
            unsigned t0 = p[0], t1 = p[32], t2 = p[160], t3 = p[192];
            if (act) {
                int dst = ed.y >> 8;
                if (dst != curDst) {
                    if (curDst >= 0) {
                        atomicAdd(&agg[(curDst - n0) * H2C + 2 * o2], ax);
                        atomicAdd(&agg[(curDst - n0) * H2C + 2 * o2 + 1], ay);
                    }
                    ax = ay = 0.0f;
                    curDst = dst;
                }
                float f0 = __int_as_float(ed.z), f1 = __int_as_float(ed.w);
                float g0 = 1.0f - f0, g1 = 1.0f - f1;
                float b0 = g0 * g1, b1 = f0 * g1, bb2 = g0 * f1, b3 = f0 * f1;
                __half2 h0 = *(__half2*)&t0, h1v = *(__half2*)&t1;
                __half2 h2 = *(__half2*)&t2, h3 = *(__half2*)&t3;
                ax = fmaf(b0, __low2float(h0), ax);  ay = fmaf(b0, __high2float(h0), ay);
                ax = fmaf(b1, __low2float(h1v), ax); ay = fmaf(b1, __high2float(h1v), ay);
                ax = fmaf(bb2, __low2float(h2), ax); ay = fmaf(bb2, __high2float(h2), ay);
                ax = fmaf(b3, __low2float(h3), ax);  ay = fmaf(b3, __high2float(h3), ay);
            }
        }
    }
    if (curDst >= 0) {
        atomicAdd(&agg[(curDst - n0) * H2C + 2 * o2], ax);
        atomicAdd(&agg[(curDst - n0) * H2C + 2 * o2 + 1], ay);
    }
    __syncthreads();

    // epilogue: h2 = relu(agg/deg + h1@root2 + b2), in place in agg
#pragma unroll
    for (int i = 0; i < 4; i++) {
        int ln = w + 4 * i;
        int n = n0 + ln;
        if (n < N) {
            float rd = 1.0f / fmaxf((float)degi[n], 1.0f);
            float v = agg[ln * H2C + lane] * rd + b2[lane];
            const float* hr = h1 + n * H1C;
#pragma unroll 8
            for (int c = 0; c < H1C; c++) v = fmaf(hr[c], root2[c * H2C + lane], v);
            agg[ln * H2C + lane] = fmaxf(v, 0.0f);
        } else {
            agg[ln * H2C + lane] = 0.0f;
        }
    }
    __syncthreads();

    // pool: one atomic per (graph,o) per block
    if (tid < H2C) {
        float run = 0.0f;
        int curg = batch[n0];
        for (int ln = 0; ln < M2; ln++) {
            int n = n0 + ln;
            if (n >= N) break;
            int gg = batch[n];
            if (gg != curg) {
                atomicAdd(&gsum[curg * H2C + tid], run);
                run = 0.0f;
                curg = gg;
            }
            run += agg[ln * H2C + tid];
        }
        atomicAdd(&gsum[curg * H2C + tid], run);
    }
}

// ---------------- head: mean, FC1+relu, FC2, log_softmax ----------------
__global__ void head_kernel(const float* __restrict__ gsum, const float* __restrict__ cnt,
                            const float* __restrict__ Wf1, const float* __restrict__ bf1,
                            const float* __restrict__ Wf2, const float* __restrict__ bf2,
                            float* __restrict__ out) {
    __shared__ float gc[H2C];
    __shared__ float t1[FCC];
    __shared__ float lg[NCLS];
    __shared__ float lse;
    int g = blockIdx.x, tid = threadIdx.x;
    if (tid < H2C) gc[tid] = gsum[g * H2C + tid] / fmaxf(cnt[g], 1.0f);
    __syncthreads();
    {
        float acc = bf1[tid];
        for (int c = 0; c < H2C; c++) acc += gc[c] * Wf1[c * FCC + tid];
        t1[tid] = fmaxf(acc, 0.0f);
    }
    __syncthreads();
    if (tid < NCLS) {
        float acc = bf2[tid];
        for (int j = 0; j < FCC; j++) acc += t1[j] * Wf2[j * NCLS + tid];
        lg[tid] = acc;
    }
    __syncthreads();
    if (tid == 0) {
        float m = lg[0];
        for (int c = 1; c < NCLS; c++) m = fmaxf(m, lg[c]);
        float s = 0.0f;
        for (int c = 0; c < NCLS; c++) s += expf(lg[c] - m);
        lse = m + logf(s);
    }
    __syncthreads();
    if (tid < NCLS) out[g * NCLS + tid] = lg[tid] - lse;
}

extern "C" void kernel_launch(void* const* d_in, const int* in_sizes, int n_in,
                              void* d_out, int out_size, void* d_ws, size_t ws_size,
                              hipStream_t stream) {
    const float* x          = (const float*)d_in[0];
    const float* edge_attr  = (const float*)d_in[1];
    const float* W1         = (const float*)d_in[2];
    const float* root1      = (const float*)d_in[3];
    const float* b1         = (const float*)d_in[4];
    const float* W2         = (const float*)d_in[5];
    const float* root2      = (const float*)d_in[6];
    const float* b2         = (const float*)d_in[7];
    const float* Wf1        = (const float*)d_in[8];
    const float* bf1        = (const float*)d_in[9];
    const float* Wf2        = (const float*)d_in[10];
    const float* bf2        = (const float*)d_in[11];
    const int*   edge_index = (const int*)d_in[12];
    const int*   batch      = (const int*)d_in[13];
    float* out = (float*)d_out;

    const int N = in_sizes[13];       // 20000
    const int E = in_sizes[12] / 2;   // 320000
    const int NB = (N + 255) / 256;   // scan blocks

    // -------- workspace layout --------
    int4*     es   = (int4*)d_ws;                        // E packed sorted edges
    unsigned* xphu = (unsigned*)(es + E);                // N*800 uints = fp16 [N][25][64]
    __half*   w2t  = (__half*)(xphu + (size_t)N * 800);  // 25*64*32 halves (100 KB)
    __half*   h1f  = w2t + KK * H2C * H1C;               // N*32 halves
    float* gsum  = (float*)(h1f + (size_t)N * H1C);      // NG*H2C  -- zero block start
    float* cnt   = gsum + NG * H2C;                      // NG
    int*   degi  = (int*)(cnt + NG);                     // N       -- zero block end
    int*   rowst = degi + N;                             // N
    int*   cur   = rowst + N;                            // N
    int*   incl  = cur + N;                              // N
    int*   bsum  = incl + N;                             // 256
    float* h1    = (float*)(bsum + 256);                 // N*H1C

    size_t zero_elems = (size_t)NG * H2C + NG + N;
    hipMemsetAsync(gsum, 0, zero_elems * sizeof(float), stream);

    deg_cnt_kernel<<<(E + 255) / 256, 256, 0, stream>>>(edge_index, E, batch, N, degi, cnt);

    scan1_kernel<<<NB, 256, 0, stream>>>(degi, N, incl, bsum);
    scan2_kernel<<<1, 256, 0, stream>>>(bsum, NB);
    scan3_kernel<<<NB, 256, 0, stream>>>(incl, degi, bsum, N, rowst, cur);

    bucket_kernel<<<(E + 255) / 256, 256, 0, stream>>>(edge_attr, edge_index, E, cur, es);
    w2t_kernel<<<(KK * H2C * H1C + 255) / 256, 256, 0, stream>>>(W2, w2t);

    l1_kernel<<<(N + M1 - 1) / M1, 256, 0, stream>>>(
        x, rowst, degi, es, W1, root1, b1, N, E, h1, h1f);

    xw2m_kernel<<<(N + 15) / 16, 256, 0, stream>>>(h1f, w2t, N, (__half*)xphu);

    l2_kernel<<<(N + M2 - 1) / M2, 256, 0, stream>>>(
        h1, rowst, degi, es, xphu, root2, b2, batch, N, E, gsum);

    head_kernel<<<NG, FCC, 0, stream>>>(gsum, cnt, Wf1, bf1, Wf2, bf2, out);
}

// Round 8
// 214.027 us; speedup vs baseline: 2.7674x; 1.5308x over previous
//
#include <hip/hip_runtime.h>
#include <hip/hip_fp16.h>
#include <math.h>

#define KK 25
#define H1C 32
#define H2C 64
#define FCC 128
#define NCLS 10
#define NG 64
#define M1 32      // nodes per block, layer-1
#define M2 16      // nodes per block, layer-2
#define NHB 128    // histogram blocks
#define HBIN 10240 // LDS histogram bins per pass (40 KB)

typedef _Float16 v8h __attribute__((ext_vector_type(8)));
typedef float v4f __attribute__((ext_vector_type(4)));

// ---------------- degree histogram: per-block LDS bins, no global atomics ----
__global__ __launch_bounds__(256) void hist_kernel(
    const int* __restrict__ edge_index, int E, int N,
    int* __restrict__ part) {            // [NHB][N]
    __shared__ int hs[HBIN];
    int b = blockIdx.x, tid = threadIdx.x;
    int per = (E + NHB - 1) / NHB;
    int beg = b * per, end = min(E, beg + per);
    for (int lo = 0; lo < N; lo += HBIN) {
        int sz = min(HBIN, N - lo);
        __syncthreads();
        for (int i = tid; i < sz; i += 256) hs[i] = 0;
        __syncthreads();
        for (int i = beg + tid; i < end; i += 256) {
            int d = edge_index[E + i] - lo;
            if ((unsigned)d < (unsigned)sz) atomicAdd(&hs[d], 1);   // ds_add
        }
        __syncthreads();
        for (int i = tid; i < sz; i += 256) part[(size_t)b * N + lo + i] = hs[i];
    }
}

__global__ void merge_kernel(const int* __restrict__ part, int N,
                             int* __restrict__ degi) {
    int n = blockIdx.x * 256 + threadIdx.x;
    if (n >= N) return;
    int s = 0;
    for (int b = 0; b < NHB; b++) s += part[(size_t)b * N + n];
    degi[n] = s;
}

// ---------------- prefix-sum (3-kernel) over degi -> rowst, cur ----------------
__global__ void scan1_kernel(const int* __restrict__ degi, int N,
                             int* __restrict__ incl, int* __restrict__ bsum) {
    __shared__ int s[256];
    int tid = threadIdx.x;
    int i = blockIdx.x * 256 + tid;
    int v = (i < N) ? degi[i] : 0;
    s[tid] = v;
    __syncthreads();
    for (int off = 1; off < 256; off <<= 1) {
        int t = (tid >= off) ? s[tid - off] : 0;
        __syncthreads();
        s[tid] += t;
        __syncthreads();
    }
    if (i < N) incl[i] = s[tid];
    if (tid == 255) bsum[blockIdx.x] = s[255];
}

__global__ void scan2_kernel(int* __restrict__ bsum, int nb) {
    __shared__ int s[256];
    int tid = threadIdx.x;
    int v = (tid < nb) ? bsum[tid] : 0;
    s[tid] = v;
    __syncthreads();
    for (int off = 1; off < 256; off <<= 1) {
        int t = (tid >= off) ? s[tid - off] : 0;
        __syncthreads();
        s[tid] += t;
        __syncthreads();
    }
    if (tid < nb) bsum[tid] = s[tid] - v;   // exclusive
}

__global__ void scan3_kernel(const int* __restrict__ incl, const int* __restrict__ degi,
                             const int* __restrict__ bsum, int N,
                             int* __restrict__ rowst, int* __restrict__ cur) {
    int i = blockIdx.x * 256 + threadIdx.x;
    if (i >= N) return;
    int r = incl[i] - degi[i] + bsum[blockIdx.x];
    rowst[i] = r;
    cur[i] = r;
}

// ---------------- bucket edges by dst; 16B packed {src, dst<<8|kbase, f0, f1} --
__global__ void bucket_kernel(const float* __restrict__ edge_attr,
                              const int* __restrict__ edge_index, int E,
                              int* __restrict__ cur, int4* __restrict__ es) {
    int e = blockIdx.x * blockDim.x + threadIdx.x;
    if (e >= E) return;
    float v0 = edge_attr[2 * e + 0] * 4.0f;
    float v1 = edge_attr[2 * e + 1] * 4.0f;
    int k0 = (int)floorf(v0); k0 = min(max(k0, 0), 3);
    int k1 = (int)floorf(v1); k1 = min(max(k1, 0), 3);
    float f0 = v0 - (float)k0, f1 = v1 - (float)k1;
    int dst = edge_index[E + e];
    int pos = atomicAdd(&cur[dst], 1);
    es[pos] = make_int4(edge_index[e], (dst << 8) | (k0 + 5 * k1),
                        __float_as_int(f0), __float_as_int(f1));
}

// ---------------- W2 -> fp16 transposed [25][64][32] (c innermost) ----------
__global__ void w2t_kernel(const float* __restrict__ W2, __half* __restrict__ W2t) {
    int idx = blockIdx.x * 256 + threadIdx.x;
    if (idx >= KK * H2C * H1C) return;
    int c = idx & 31, o = (idx >> 5) & 63, k = idx >> 11;
    W2t[idx] = __float2half(W2[(k * H1C + c) * H2C + o]);
}

// ---------------- layer 1: CSR gather, register accumulate, boundary flush ----
__global__ __launch_bounds__(256) void l1_kernel(
    const float* __restrict__ x,
    const int* __restrict__ rowst, const int* __restrict__ degi,
    const int4* __restrict__ es,
    const float* __restrict__ W1, const float* __restrict__ root1,
    const float* __restrict__ b1, int N, int E,
    float* __restrict__ h1, __half* __restrict__ h1f) {
    __shared__ float w1s[KK * H1C];
    __shared__ float agg1[M1 * H1C];
    __shared__ int4 eb[8][32];
    __shared__ float xb[8][32];
    int tid = threadIdx.x;
    for (int i = tid; i < KK * H1C; i += 256) w1s[i] = W1[i];
    for (int i = tid; i < M1 * H1C; i += 256) agg1[i] = 0.0f;
    __syncthreads();
    int g = tid >> 5, o = tid & 31;
    int n0 = blockIdx.x * M1;
    int blkBeg = rowst[n0];
    int blkEnd = (n0 + M1 < N) ? rowst[n0 + M1] : E;
    int total = blkEnd - blkBeg;
    int per = (total + 7) >> 3;
    int wBeg = blkBeg + g * per;
    int wEnd = min(blkEnd, wBeg + per);
    int curDst = -1;
    float acc = 0.0f;
    for (int base = wBeg; base < wEnd; base += 32) {
        int m = min(32, wEnd - base);
        if (o < m) {
            int4 ed = es[base + o];
            eb[g][o] = ed;
            xb[g][o] = x[ed.x];
        }
        for (int j = 0; j < m; j++) {
            int4 ed = eb[g][j];
            float xs = xb[g][j];
            int dst = ed.y >> 8;
            if (dst != curDst) {
                if (curDst >= 0) atomicAdd(&agg1[(curDst - n0) * H1C + o], acc);
                acc = 0.0f;
                curDst = dst;
            }
            float f0 = __int_as_float(ed.z), f1 = __int_as_float(ed.w);
            float g0 = 1.0f - f0, g1 = 1.0f - f1;
            int kb = (ed.y & 0xff) << 5;
            float coef = g0 * g1 * w1s[kb + o] + f0 * g1 * w1s[kb + 32 + o] +
                         g0 * f1 * w1s[kb + 160 + o] + f0 * f1 * w1s[kb + 192 + o];
            acc = fmaf(xs, coef, acc);
        }
    }
    if (curDst >= 0) atomicAdd(&agg1[(curDst - n0) * H1C + o], acc);
    __syncthreads();
#pragma unroll
    for (int i = 0; i < 4; i++) {
        int ln = g + 8 * i;
        int n = n0 + ln;
        if (n < N) {
            float rdeg = 1.0f / fmaxf((float)degi[n], 1.0f);
            float hv = fmaxf(agg1[ln * H1C + o] * rdeg + x[n] * root1[o] + b1[o], 0.0f);
            h1[n * H1C + o] = hv;
            h1f[n * H1C + o] = __float2half(hv);
        }
    }
}

// ---------------- xW2 via MFMA: [N][25][64] fp16 = h1f @ W2t ----------------
__global__ __launch_bounds__(256) void xw2m_kernel(
    const __half* __restrict__ h1f,   // [N][32]
    const __half* __restrict__ W2t,   // [25][64][32] (c innermost)
    int N, __half* __restrict__ xph) {  // [N][25][64]
    int wv = threadIdx.x >> 6;
    int lane = threadIdx.x & 63;
    int r15 = lane & 15, quad = lane >> 4;
    int n0 = blockIdx.x * 16;
    int o0 = wv * 16;
    v8h afrag = {};
    int an = n0 + r15;
    if (an < N) afrag = *(const v8h*)(h1f + (size_t)an * H1C + quad * 8);
    for (int k = 0; k < KK; k++) {
        v8h bfrag = *(const v8h*)(W2t + ((k << 6) + o0 + r15) * H1C + quad * 8);
        v4f acc = {};
        acc = __builtin_amdgcn_mfma_f32_16x16x32_f16(afrag, bfrag, acc, 0, 0, 0);
#pragma unroll
        for (int r = 0; r < 4; r++) {
            int mn = n0 + quad * 4 + r;
            if (mn < N)
                xph[(size_t)mn * (KK * H2C) + (k << 6) + o0 + r15] = __float2half(acc[r]);
        }
    }
}

// ---------------- layer 2: half2-packed gather + segment accumulate ----------
__global__ __launch_bounds__(256) void l2_kernel(
    const float* __restrict__ h1,
    const int* __restrict__ rowst, const int* __restrict__ degi,
    const int4* __restrict__ es,
    const unsigned* __restrict__ xphu,  // [N][25][32] uints (=2 halves)
    const float* __restrict__ root2, const float* __restrict__ b2,
    const int* __restrict__ batch,
    int N, int E, float* __restrict__ gsum) {
    __shared__ float agg[M2 * H2C];
    __shared__ int4 eb[4][64];
    int tid = threadIdx.x;
    for (int i = tid; i < M2 * H2C; i += 256) agg[i] = 0.0f;
    __syncthreads();
    int w = tid >> 6, lane = tid & 63;
    int o2 = lane & 31, eh = lane >> 5;
    int n0 = blockIdx.x * M2;
    int blkBeg = rowst[n0];
    int blkEnd = (n0 + M2 < N) ? rowst[n0 + M2] : E;
    int total = blkEnd - blkBeg;
    int per = (total + 3) >> 2;
    int wBeg = blkBeg + w * per;
    int wEnd = min(blkEnd, wBeg + per);
    int curDst = -1;
    float ax = 0.0f, ay = 0.0f;
    for (int base = wBeg; base < wEnd; base += 64) {
        int m = min(64, wEnd - base);
        if (lane < m) eb[w][lane] = es[base + lane];
        for (int j = 0; j < m; j += 2) {
            int jj = j + eh;
            bool act = jj < m;
            int4 ed = eb[w][act ? jj : j];
            const unsigned* p = xphu + (size_t)ed.x * (KK * H2C / 2) +
                                ((ed.y & 0xff) << 5) + o2;
            unsigned t0 = p[0], t1 = p[32], t2 = p[160], t3 = p[192];
            if (act) {
                int dst = ed.y >> 8;
                if (dst != curDst) {
                    if (curDst >= 0) {
                        atomicAdd(&agg[(curDst - n0) * H2C + 2 * o2], ax);
                        atomicAdd(&agg[(curDst - n0) * H2C + 2 * o2 + 1], ay);
                    }
                    ax = ay = 0.0f;
                    curDst = dst;
                }
                float f0 = __int_as_float(ed.z), f1 = __int_as_float(ed.w);
                float g0 = 1.0f - f0, g1 = 1.0f - f1;
                float b0 = g0 * g1, b1 = f0 * g1, bb2 = g0 * f1, b3 = f0 * f1;
                __half2 h0 = *(__half2*)&t0, h1v = *(__half2*)&t1;
                __half2 h2 = *(__half2*)&t2, h3 = *(__half2*)&t3;
                ax = fmaf(b0, __low2float(h0), ax);  ay = fmaf(b0, __high2float(h0), ay);
                ax = fmaf(b1, __low2float(h1v), ax); ay = fmaf(b1, __high2float(h1v), ay);
                ax = fmaf(bb2, __low2float(h2), ax); ay = fmaf(bb2, __high2float(h2), ay);
                ax = fmaf(b3, __low2float(h3), ax);  ay = fmaf(b3, __high2float(h3), ay);
            }
        }
    }
    if (curDst >= 0) {
        atomicAdd(&agg[(curDst - n0) * H2C + 2 * o2], ax);
        atomicAdd(&agg[(curDst - n0) * H2C + 2 * o2 + 1], ay);
    }
    __syncthreads();

    // epilogue: h2 = relu(agg/deg + h1@root2 + b2), in place in agg
#pragma unroll
    for (int i = 0; i < 4; i++) {
        int ln = w + 4 * i;
        int n = n0 + ln;
        if (n < N) {
            float rd = 1.0f / fmaxf((float)degi[n], 1.0f);
            float v = agg[ln * H2C + lane] * rd + b2[lane];
            const float* hr = h1 + n * H1C;
#pragma unroll 8
            for (int c = 0; c < H1C; c++) v = fmaf(hr[c], root2[c * H2C + lane], v);
            agg[ln * H2C + lane] = fmaxf(v, 0.0f);
        } else {
            agg[ln * H2C + lane] = 0.0f;
        }
    }
    __syncthreads();

    // pool: one atomic per (graph,o) per block
    if (tid < H2C) {
        float run = 0.0f;
        int curg = batch[n0];
        for (int ln = 0; ln < M2; ln++) {
            int n = n0 + ln;
            if (n >= N) break;
            int gg = batch[n];
            if (gg != curg) {
                atomicAdd(&gsum[curg * H2C + tid], run);
                run = 0.0f;
                curg = gg;
            }
            run += agg[ln * H2C + tid];
        }
        atomicAdd(&gsum[curg * H2C + tid], run);
    }
}

// ---------------- head: count via binary search, FC1+relu, FC2, log_softmax --
__global__ void head_kernel(const float* __restrict__ gsum,
                            const int* __restrict__ batch, int N,
                            const float* __restrict__ Wf1, const float* __restrict__ bf1,
                            const float* __restrict__ Wf2, const float* __restrict__ bf2,
                            float* __restrict__ out) {
    __shared__ float gc[H2C];
    __shared__ float t1[FCC];
    __shared__ float lg[NCLS];
    __shared__ float lse;
    __shared__ float scnt;
    int g = blockIdx.x, tid = threadIdx.x;
    if (tid == 0) {
        int lo = 0, hi = N;
        while (lo < hi) { int m = (lo + hi) >> 1; if (batch[m] < g) lo = m + 1; else hi = m; }
        int lb = lo;
        lo = 0; hi = N;
        while (lo < hi) { int m = (lo + hi) >> 1; if (batch[m] <= g) lo = m + 1; else hi = m; }
        scnt = (float)(lo - lb);
    }
    __syncthreads();
    if (tid < H2C) gc[tid] = gsum[g * H2C + tid] / fmaxf(scnt, 1.0f);
    __syncthreads();
    {
        float acc = bf1[tid];
        for (int c = 0; c < H2C; c++) acc += gc[c] * Wf1[c * FCC + tid];
        t1[tid] = fmaxf(acc, 0.0f);
    }
    __syncthreads();
    if (tid < NCLS) {
        float acc = bf2[tid];
        for (int j = 0; j < FCC; j++) acc += t1[j] * Wf2[j * NCLS + tid];
        lg[tid] = acc;
    }
    __syncthreads();
    if (tid == 0) {
        float m = lg[0];
        for (int c = 1; c < NCLS; c++) m = fmaxf(m, lg[c]);
        float s = 0.0f;
        for (int c = 0; c < NCLS; c++) s += expf(lg[c] - m);
        lse = m + logf(s);
    }
    __syncthreads();
    if (tid < NCLS) out[g * NCLS + tid] = lg[tid] - lse;
}

extern "C" void kernel_launch(void* const* d_in, const int* in_sizes, int n_in,
                              void* d_out, int out_size, void* d_ws, size_t ws_size,
                              hipStream_t stream) {
    const float* x          = (const float*)d_in[0];
    const float* edge_attr  = (const float*)d_in[1];
    const float* W1         = (const float*)d_in[2];
    const float* root1      = (const float*)d_in[3];
    const float* b1         = (const float*)d_in[4];
    const float* W2         = (const float*)d_in[5];
    const float* root2      = (const float*)d_in[6];
    const float* b2         = (const float*)d_in[7];
    const float* Wf1        = (const float*)d_in[8];
    const float* bf1        = (const float*)d_in[9];
    const float* Wf2        = (const float*)d_in[10];
    const float* bf2        = (const float*)d_in[11];
    const int*   edge_index = (const int*)d_in[12];
    const int*   batch      = (const int*)d_in[13];
    float* out = (float*)d_out;

    const int N = in_sizes[13];       // 20000
    const int E = in_sizes[12] / 2;   // 320000
    const int NB = (N + 255) / 256;   // scan blocks

    // -------- workspace layout --------
    int4*     es   = (int4*)d_ws;                        // E packed sorted edges
    unsigned* xphu = (unsigned*)(es + E);                // N*800 uints = fp16 [N][25][64]
    __half*   w2t  = (__half*)(xphu + (size_t)N * 800);  // 25*64*32 halves
    __half*   h1f  = w2t + KK * H2C * H1C;               // N*32 halves
    float* gsum  = (float*)(h1f + (size_t)N * H1C);      // NG*H2C  -- zeroed
    int*   degi  = (int*)(gsum + NG * H2C);              // N
    int*   rowst = degi + N;                             // N
    int*   cur   = rowst + N;                            // N
    int*   incl  = cur + N;                              // N
    int*   bsum  = incl + N;                             // 256
    float* h1    = (float*)(bsum + 256);                 // N*H1C
    int*   part  = (int*)(h1 + (size_t)N * H1C);         // NHB*N

    hipMemsetAsync(gsum, 0, (size_t)NG * H2C * sizeof(float), stream);

    hist_kernel<<<NHB, 256, 0, stream>>>(edge_index, E, N, part);
    merge_kernel<<<NB, 256, 0, stream>>>(part, N, degi);

    scan1_kernel<<<NB, 256, 0, stream>>>(degi, N, incl, bsum);
    scan2_kernel<<<1, 256, 0, stream>>>(bsum, NB);
    scan3_kernel<<<NB, 256, 0, stream>>>(incl, degi, bsum, N, rowst, cur);

    bucket_kernel<<<(E + 255) / 256, 256, 0, stream>>>(edge_attr, edge_index, E, cur, es);
    w2t_kernel<<<(KK * H2C * H1C + 255) / 256, 256, 0, stream>>>(W2, w2t);

    l1_kernel<<<(N + M1 - 1) / M1, 256, 0, stream>>>(
        x, rowst, degi, es, W1, root1, b1, N, E, h1, h1f);

    xw2m_kernel<<<(N + 15) / 16, 256, 0, stream>>>(h1f, w2t, N, (__half*)xphu);

    l2_kernel<<<(N + M2 - 1) / M2, 256, 0, stream>>>(
        h1, rowst, degi, es, xphu, root2, b2, batch, N, E, gsum);

    head_kernel<<<NG, FCC, 0, stream>>>(gsum, batch, N, Wf1, bf1, Wf2, bf2, out);
}